// Round 2
// baseline (2136.374 us; speedup 1.0000x reference)
//
#include <hip/hip_runtime.h>

typedef unsigned short u16;
typedef unsigned int u32;
typedef __bf16 bf16x8 __attribute__((ext_vector_type(8)));
typedef float f32x4 __attribute__((ext_vector_type(4)));

#define N 4096
#define KD 128
#define NSTRIP 16
#define G 4            // cols per lane
#define W 256          // strip width = 64*G
#define CH 64          // rows (steps) per block
#define NCHUNK 64      // N/CH
#define NBLK 65        // ceil((N+63)/CH)
#define TOTSTEP 4159   // N + 63
#define HUGEV 3.0e38f
#define TS 128
#define PADK 136       // padded LDS K-stride

__device__ __forceinline__ u16 f2bf(float v) {
  u32 u = __float_as_uint(v);
  u += 0x7fffu + ((u >> 16) & 1u);   // RNE
  return (u16)(u >> 16);
}
__device__ __forceinline__ float bf2f(u16 b) { return __uint_as_float(((u32)b) << 16); }
__device__ __forceinline__ float bfround(float v) { return bf2f(f2bf(v)); }

__device__ __forceinline__ void gload_lds16(const void* g, void* l) {
  __builtin_amdgcn_global_load_lds((const __attribute__((address_space(1))) u32*)g,
                                   (__attribute__((address_space(3))) u32*)l, 16, 0, 0);
}

// ---------------- norms (of bf16-rounded points) + flag init ----------------
__global__ __launch_bounds__(256) void norms_kernel(const float* __restrict__ pred,
                                                    const float* __restrict__ tgt,
                                                    float* __restrict__ na, float* __restrict__ nb,
                                                    int* __restrict__ prog) {
  if (blockIdx.x == 0 && threadIdx.x < NSTRIP) prog[threadIdx.x] = 0;
  int gw = blockIdx.x * 4 + (threadIdx.x >> 6);   // one wave per row, 8192 rows
  int lane = threadIdx.x & 63;
  const float* base = (gw < N) ? (pred + (size_t)gw * KD) : (tgt + (size_t)(gw - N) * KD);
  float2 v = ((const float2*)base)[lane];
  float x = bfround(v.x), y = bfround(v.y);
  float s = x * x + y * y;
  #pragma unroll
  for (int off = 32; off > 0; off >>= 1) s += __shfl_xor(s, off);
  if (lane == 0) { if (gw < N) na[gw] = s; else nb[gw - N] = s; }
}

// ---------------- C2 = |a|^2 + |b|^2 - 2 a.b  (bf16 out) ----------------
__global__ __launch_bounds__(256) void gemm_kernel(const float* __restrict__ A, const float* __restrict__ B,
                                                   const float* __restrict__ na, const float* __restrict__ nb,
                                                   u16* __restrict__ C2) {
  __shared__ u16 As[TS * PADK];
  __shared__ u16 Bs[TS * PADK];
  const int bi = blockIdx.y, bj = blockIdx.x;
  const int tid = threadIdx.x;
  {
    int row = tid >> 1, half = (tid & 1) * 64;
    const float* ga = A + (size_t)(bi * TS + row) * KD + half;
    const float* gb = B + (size_t)(bj * TS + row) * KD + half;
    u16* la = As + row * PADK + half;
    u16* lb = Bs + row * PADK + half;
    #pragma unroll
    for (int v = 0; v < 16; ++v) {
      float4 fa = ((const float4*)ga)[v];
      float4 fb = ((const float4*)gb)[v];
      ushort4 ua = make_ushort4(f2bf(fa.x), f2bf(fa.y), f2bf(fa.z), f2bf(fa.w));
      ushort4 ub = make_ushort4(f2bf(fb.x), f2bf(fb.y), f2bf(fb.z), f2bf(fb.w));
      *(ushort4*)(la + v * 4) = ua;
      *(ushort4*)(lb + v * 4) = ub;
    }
  }
  __syncthreads();
  const int wid = tid >> 6, lane = tid & 63;
  const int wr = (wid >> 1) * 64, wc = (wid & 1) * 64;
  const int l15 = lane & 15, l4 = lane >> 4;
  f32x4 acc[4][4] = {};
  #pragma unroll
  for (int ks = 0; ks < 4; ++ks) {
    bf16x8 af[4], bq[4];
    const int ko = ks * 32 + l4 * 8;
    #pragma unroll
    for (int m = 0; m < 4; ++m) af[m] = *(const bf16x8*)(As + (wr + m * 16 + l15) * PADK + ko);
    #pragma unroll
    for (int n = 0; n < 4; ++n) bq[n] = *(const bf16x8*)(Bs + (wc + n * 16 + l15) * PADK + ko);
    #pragma unroll
    for (int m = 0; m < 4; ++m)
      #pragma unroll
      for (int n = 0; n < 4; ++n)
        acc[m][n] = __builtin_amdgcn_mfma_f32_16x16x32_bf16(af[m], bq[n], acc[m][n], 0, 0, 0);
  }
  #pragma unroll
  for (int m = 0; m < 4; ++m) {
    const int r0 = bi * TS + wr + m * 16 + l4 * 4;
    #pragma unroll
    for (int n = 0; n < 4; ++n) {
      const int col = bj * TS + wc + n * 16 + l15;
      const float nbv = nb[col];
      #pragma unroll
      for (int e = 0; e < 4; ++e) {
        const int r = r0 + e;
        float d2v = na[r] + nbv - 2.0f * acc[m][n][e];
        d2v = fmaxf(d2v, 0.0f);
        C2[(size_t)r * N + col] = f2bf(d2v);
      }
    }
  }
}

// ---------------- wavefront DP over squared distances ----------------
// 16 strips x 256 cols; 1 wave per strip; lane owns G=4 adjacent cols.
// D[i][j] = med3(left, c, max(min(up, upleft), c));  final = sqrt(D[N-1][N-1]).
__global__ __launch_bounds__(64) void dp_kernel(const u16* __restrict__ C2, float* __restrict__ edge,
                                                int* __restrict__ prog, float* __restrict__ out) {
  __shared__ u16 clds[3 * CH * W];   // 96 KB triple-buffered c2 window
  __shared__ float elds[CH];
  const int bid = blockIdx.x;
  const int S = ((bid & 7) << 1) | (bid >> 3);
  const int lane = threadIdx.x;
  const u16* cbase = C2 + (size_t)S * W;
  const bool col0lane = (S == 0 && lane == 0);

  int i0 = -lane;
  int slot = (i0 + 192) % 192;
  int caddr = slot * (W * 2) + lane * (G * 2);

  if (S == 0) elds[lane] = (lane == 0) ? -HUGEV : HUGEV;   // row-0 seed: D[0][0]=c[0][0]

  float D0 = HUGEV, D1 = HUGEV, D2 = HUGEV, D3 = HUGEV, Lp = HUGEV;

  // prologue: stage chunk 0
  {
    const int lrow = lane >> 5, lcol = (lane & 31) * 8;
    const u16* g0 = cbase + (size_t)lrow * N + lcol;
    u16* l0 = clds;
    #pragma unroll
    for (int n = 0; n < 32; ++n) gload_lds16(g0 + (size_t)(2 * n) * N, l0 + n * 512);
  }

  for (int q = 0; q < NBLK; ++q) {
    const int s_lo = q * CH;
    const int s_hi = (s_lo + CH < TOTSTEP) ? (s_lo + CH) : TOTSTEP;

    // (a) edge wait + load (consumer side)
    if (S > 0 && s_lo < N) {
      const int needed = (s_hi < N) ? s_hi : N;
      int it = 0;
      while (__hip_atomic_load(prog + (S - 1), __ATOMIC_ACQUIRE, __HIP_MEMORY_SCOPE_AGENT) < needed) {
        __builtin_amdgcn_s_sleep(8);
        if (++it > (1 << 22)) break;   // deadlock safety valve
      }
      const int er = s_lo + lane;
      float ev = HUGEV;
      if (er < N)
        ev = __hip_atomic_load(edge + (size_t)(S - 1) * N + er, __ATOMIC_RELAXED, __HIP_MEMORY_SCOPE_AGENT);
      elds[lane] = ev;
    }
    if (S == 0 && q == 1 && lane == 0) elds[0] = HUGEV;   // restore slot 0 after row 0

    // (b) chunk q arrived (issued last block)
    asm volatile("s_waitcnt vmcnt(0)" ::: "memory");

    // (c) prefetch chunk q+1
    if (q + 1 < NCHUNK) {
      const int buf = (q + 1) % 3;
      const u16* gsrc = cbase + (size_t)(q + 1) * CH * N;
      u16* ldst = clds + buf * (CH * W);
      const int lrow = lane >> 5, lcol = (lane & 31) * 8;
      const u16* g0 = gsrc + (size_t)lrow * N + lcol;
      #pragma unroll
      for (int n = 0; n < 32; ++n) gload_lds16(g0 + (size_t)(2 * n) * N, ldst + n * 512);
    }

    // ensure elds writes visible to all lanes (single wave; doesn't drain vmcnt)
    asm volatile("s_waitcnt lgkmcnt(0)" ::: "memory");

    // (d) diagonal steps
    #pragma unroll 4
    for (int s = s_lo; s < s_hi; ++s) {
      const ushort4 cu = *(const ushort4*)((const char*)clds + caddr);
      caddr += W * 2;
      if (caddr >= 3 * CH * W * 2) caddr -= 3 * CH * W * 2;
      const int i = s - lane;
      const bool act = (u32)i < (u32)N;
      const float e = elds[s & (CH - 1)];
      float Lc = __shfl_up(D3, 1);
      if (lane == 0) Lc = e;
      const float c0 = bf2f(cu.x), c1 = bf2f(cu.y), c2 = bf2f(cu.z), c3 = bf2f(cu.w);
      const float h0 = fmaxf(fminf(D0, Lp), c0);
      const float h1 = fmaxf(fminf(D1, D0), c1);
      const float h2 = fmaxf(fminf(D2, D1), c2);
      const float h3 = fmaxf(fminf(D3, D2), c3);
      float x = __builtin_amdgcn_fmed3f(Lc, c0, h0);
      const float n0 = x;
      x = __builtin_amdgcn_fmed3f(x, c1, h1);
      const float n1 = x;
      x = __builtin_amdgcn_fmed3f(x, c2, h2);
      const float n2 = x;
      x = __builtin_amdgcn_fmed3f(x, c3, h3);
      const float n3 = x;
      Lp = col0lane ? HUGEV : Lc;   // col-0 has no upleft: keep +inf (fixes row-1 col-0 bug)
      if (act) { D0 = n0; D1 = n1; D2 = n2; D3 = n3; }
      if (act && lane == 63)
        __hip_atomic_store(edge + (size_t)S * N + i, n3, __ATOMIC_RELAXED, __HIP_MEMORY_SCOPE_AGENT);
    }

    // (e) publish progress (producer side)
    if (lane == 63) {
      const int done = s_hi - 63;   // rows 0..s_hi-64 complete at right edge
      __hip_atomic_store(prog + S, done, __ATOMIC_RELEASE, __HIP_MEMORY_SCOPE_AGENT);
    }
  }

  if (S == NSTRIP - 1 && lane == 63) out[0] = sqrtf(fmaxf(D3, 0.0f));
}

extern "C" void kernel_launch(void* const* d_in, const int* in_sizes, int n_in,
                              void* d_out, int out_size, void* d_ws, size_t ws_size,
                              hipStream_t stream) {
  const float* pred = (const float*)d_in[0];
  const float* tgt  = (const float*)d_in[1];
  char* ws = (char*)d_ws;
  u16* C2   = (u16*)ws;                                   // 32 MB
  float* na = (float*)(ws + (size_t)N * N * 2);           // 16 KB
  float* nb = na + N;                                     // 16 KB
  float* edge = nb + N;                                   // 256 KB
  int* prog = (int*)(edge + (size_t)NSTRIP * N);          // 64 B
  float* out = (float*)d_out;

  hipLaunchKernelGGL(norms_kernel, dim3(2048), dim3(256), 0, stream, pred, tgt, na, nb, prog);
  hipLaunchKernelGGL(gemm_kernel, dim3(32, 32), dim3(256), 0, stream, pred, tgt, na, nb, C2);
  hipLaunchKernelGGL(dp_kernel, dim3(NSTRIP), dim3(64), 0, stream, C2, edge, prog, out);
}

// Round 3
// 587.007 us; speedup vs baseline: 3.6394x; 3.6394x over previous
//
#include <hip/hip_runtime.h>

typedef unsigned short u16;
typedef unsigned int u32;
typedef __bf16 bf16x8 __attribute__((ext_vector_type(8)));
typedef float f32x4 __attribute__((ext_vector_type(4)));

#define N 4096
#define KD 128
#define NSTRIP 16
#define G 4              // cols per lane
#define W 256            // strip width (u16 per row = 512B)
#define ROWB 512         // bytes per LDS row
#define CH 64            // rows per chunk/block
#define NCHUNK 64
#define NBLK 65
#define WINROWS 192      // 3-chunk rolling window
#define LDSROWS 200      // +8 mirror rows
#define TOTSTEP 4159     // N + 63
#define HUGEV 3.0e38f
#define TS 128
#define PADK 136

__device__ __forceinline__ u16 f2bf(float v) {
  u32 u = __float_as_uint(v);
  u += 0x7fffu + ((u >> 16) & 1u);   // RNE
  return (u16)(u >> 16);
}
__device__ __forceinline__ float bf2f(u16 b) { return __uint_as_float(((u32)b) << 16); }
__device__ __forceinline__ float bfround(float v) { return bf2f(f2bf(v)); }

// lane l gets src[l-1]; lane 0 keeps `oldv`. v_mov_b32_dpp wave_shr:1 (full-rate VALU).
__device__ __forceinline__ float dpp_shr1(float oldv, float src) {
  return __int_as_float(__builtin_amdgcn_update_dpp(
      __float_as_int(oldv), __float_as_int(src), 0x138, 0xF, 0xF, false));
}

__device__ __forceinline__ void gload_lds16(const void* g, void* l) {
  __builtin_amdgcn_global_load_lds((const __attribute__((address_space(1))) u32*)g,
                                   (__attribute__((address_space(3))) u32*)l, 16, 0, 0);
}

// ---------------- norms (of bf16-rounded points) + flag init ----------------
__global__ __launch_bounds__(256) void norms_kernel(const float* __restrict__ pred,
                                                    const float* __restrict__ tgt,
                                                    float* __restrict__ na, float* __restrict__ nb,
                                                    int* __restrict__ prog) {
  if (blockIdx.x == 0 && threadIdx.x < NSTRIP) prog[threadIdx.x] = 0;
  int gw = blockIdx.x * 4 + (threadIdx.x >> 6);
  int lane = threadIdx.x & 63;
  const float* base = (gw < N) ? (pred + (size_t)gw * KD) : (tgt + (size_t)(gw - N) * KD);
  float2 v = ((const float2*)base)[lane];
  float x = bfround(v.x), y = bfround(v.y);
  float s = x * x + y * y;
  #pragma unroll
  for (int off = 32; off > 0; off >>= 1) s += __shfl_xor(s, off);
  if (lane == 0) { if (gw < N) na[gw] = s; else nb[gw - N] = s; }
}

// ---------------- C2 = |a|^2 + |b|^2 - 2 a.b  (bf16 out) ----------------
__global__ __launch_bounds__(256) void gemm_kernel(const float* __restrict__ A, const float* __restrict__ B,
                                                   const float* __restrict__ na, const float* __restrict__ nb,
                                                   u16* __restrict__ C2) {
  __shared__ u16 As[TS * PADK];
  __shared__ u16 Bs[TS * PADK];
  const int bi = blockIdx.y, bj = blockIdx.x;
  const int tid = threadIdx.x;
  {
    int row = tid >> 1, half = (tid & 1) * 64;
    const float* ga = A + (size_t)(bi * TS + row) * KD + half;
    const float* gb = B + (size_t)(bj * TS + row) * KD + half;
    u16* la = As + row * PADK + half;
    u16* lb = Bs + row * PADK + half;
    #pragma unroll
    for (int v = 0; v < 16; ++v) {
      float4 fa = ((const float4*)ga)[v];
      float4 fb = ((const float4*)gb)[v];
      *(ushort4*)(la + v * 4) = make_ushort4(f2bf(fa.x), f2bf(fa.y), f2bf(fa.z), f2bf(fa.w));
      *(ushort4*)(lb + v * 4) = make_ushort4(f2bf(fb.x), f2bf(fb.y), f2bf(fb.z), f2bf(fb.w));
    }
  }
  __syncthreads();
  const int wid = tid >> 6, lane = tid & 63;
  const int wr = (wid >> 1) * 64, wc = (wid & 1) * 64;
  const int l15 = lane & 15, l4 = lane >> 4;
  f32x4 acc[4][4] = {};
  #pragma unroll
  for (int ks = 0; ks < 4; ++ks) {
    bf16x8 af[4], bq[4];
    const int ko = ks * 32 + l4 * 8;
    #pragma unroll
    for (int m = 0; m < 4; ++m) af[m] = *(const bf16x8*)(As + (wr + m * 16 + l15) * PADK + ko);
    #pragma unroll
    for (int n = 0; n < 4; ++n) bq[n] = *(const bf16x8*)(Bs + (wc + n * 16 + l15) * PADK + ko);
    #pragma unroll
    for (int m = 0; m < 4; ++m)
      #pragma unroll
      for (int n = 0; n < 4; ++n)
        acc[m][n] = __builtin_amdgcn_mfma_f32_16x16x32_bf16(af[m], bq[n], acc[m][n], 0, 0, 0);
  }
  #pragma unroll
  for (int m = 0; m < 4; ++m) {
    const int r0 = bi * TS + wr + m * 16 + l4 * 4;
    #pragma unroll
    for (int n = 0; n < 4; ++n) {
      const int col = bj * TS + wc + n * 16 + l15;
      const float nbv = nb[col];
      #pragma unroll
      for (int e = 0; e < 4; ++e) {
        const int r = r0 + e;
        float d2v = fmaxf(na[r] + nbv - 2.0f * acc[m][n][e], 0.0f);
        C2[(size_t)r * N + col] = f2bf(d2v);
      }
    }
  }
}

// ---------------- wavefront DP over squared distances ----------------
#define STEP_F(CU, EV) { \
  const float c0 = bf2f((CU).x), c1 = bf2f((CU).y), c2 = bf2f((CU).z), c3 = bf2f((CU).w); \
  const float Lc = dpp_shr1((EV), D3); \
  const float h0 = fmaxf(fminf(D0, Lp), c0); \
  const float h1 = fmaxf(fminf(D1, D0), c1); \
  const float h2 = fmaxf(fminf(D2, D1), c2); \
  const float h3 = fmaxf(fminf(D3, D2), c3); \
  float x = __builtin_amdgcn_fmed3f(Lc, c0, h0); D0 = x; \
  x = __builtin_amdgcn_fmed3f(x, c1, h1); D1 = x; \
  x = __builtin_amdgcn_fmed3f(x, c2, h2); D2 = x; \
  x = __builtin_amdgcn_fmed3f(x, c3, h3); D3 = x; \
  Lp = Lc; \
}

__global__ __launch_bounds__(64) void dp_kernel(const u16* __restrict__ C2, float* __restrict__ edge,
                                                int* __restrict__ prog, float* __restrict__ out) {
  __shared__ u16 clds[LDSROWS * W];                 // 100 KB rolling window (+mirror)
  __shared__ __align__(16) float elds[CH];
  __shared__ __align__(16) float eout[CH];
  const int bid = blockIdx.x;
  const int S = ((bid & 7) << 1) | (bid >> 3);
  const int lane = threadIdx.x;
  const u16* cbase = C2 + (size_t)S * W;
  const char* clb = (const char*)clds;
  const bool s0 = (S == 0);
  const bool do_edge = (S != NSTRIP - 1);
  const bool edge63 = do_edge && (lane == 63);

  if (s0) elds[lane] = (lane == 0) ? -HUGEV : HUGEV;   // row-0 seed

  float D0 = HUGEV, D1 = HUGEV, D2 = HUGEV, D3 = HUGEV, Lp = HUGEV;

  auto STAGE = [&](int q) {
    const int lrow = lane >> 5, lcol = (lane & 31) * 8;
    const u16* g0 = cbase + (size_t)(q * CH + lrow) * N + lcol;
    u16* l0 = clds + (q % 3) * (CH * W);
    #pragma unroll
    for (int n = 0; n < 32; ++n) gload_lds16(g0 + (size_t)(2 * n) * N, l0 + n * 512);
    if ((q % 3) == 0) {   // mirror rows 0..7 -> LDS rows 192..199
      u16* lm = clds + WINROWS * W;
      #pragma unroll
      for (int n = 0; n < 4; ++n) gload_lds16(g0 + (size_t)(2 * n) * N, lm + n * 512);
    }
  };

  STAGE(0);
  STAGE(1);

  for (int q = 0; q < NBLK; ++q) {
    const int s_lo = q * CH;

    // (a) consumer: wait for producer strip, load edge rows
    if (S > 0 && s_lo < N) {
      const int needed = (s_lo + CH < N) ? (s_lo + CH) : N;
      int it = 0;
      while (__hip_atomic_load(prog + (S - 1), __ATOMIC_ACQUIRE, __HIP_MEMORY_SCOPE_AGENT) < needed) {
        __builtin_amdgcn_s_sleep(1);
        if (++it > (1 << 22)) break;
      }
      const int er = s_lo + lane;
      float ev = (er < N)
          ? __hip_atomic_load(edge + (size_t)(S - 1) * N + er, __ATOMIC_RELAXED, __HIP_MEMORY_SCOPE_AGENT)
          : HUGEV;
      elds[lane] = ev;
    }
    if (s0 && q == 1 && lane == 0) elds[0] = HUGEV;   // restore after row-0 seed

    // (b) drain: chunk q resident (staged >=1 block ago), elds loads done
    asm volatile("s_waitcnt vmcnt(0)" ::: "memory");
    asm volatile("s_waitcnt lgkmcnt(0)" ::: "memory");
    __builtin_amdgcn_sched_barrier(0);

    // (c) per-lane LDS byte addr of first read: row (s_lo - lane) mod 192, col lane*8B
    int base = ((64 * (q % 3) + WINROWS - lane) % WINROWS) * ROWB + lane * (G * 2);

    if (q != 0 && q != NBLK - 1) {
      // -------- fast path: all lanes active every step --------
      #pragma unroll 1
      for (int g = 0; g < 8; ++g) {
        const float4 ea = *(const float4*)(elds + g * 8);
        const float4 eb = *(const float4*)(elds + g * 8 + 4);
        const ushort4 cv0 = *(const ushort4*)(clb + base);
        const ushort4 cv1 = *(const ushort4*)(clb + base + 512);
        const ushort4 cv2 = *(const ushort4*)(clb + base + 1024);
        const ushort4 cv3 = *(const ushort4*)(clb + base + 1536);
        const ushort4 cv4 = *(const ushort4*)(clb + base + 2048);
        const ushort4 cv5 = *(const ushort4*)(clb + base + 2560);
        const ushort4 cv6 = *(const ushort4*)(clb + base + 3072);
        const ushort4 cv7 = *(const ushort4*)(clb + base + 3584);
        base += 8 * ROWB;
        if (base >= WINROWS * ROWB) base -= WINROWS * ROWB;
        float t0, t1, t2, t3, t4, t5, t6, t7;
        STEP_F(cv0, ea.x); t0 = D3;
        STEP_F(cv1, ea.y); t1 = D3;
        STEP_F(cv2, ea.z); t2 = D3;
        STEP_F(cv3, ea.w); t3 = D3;
        STEP_F(cv4, eb.x); t4 = D3;
        STEP_F(cv5, eb.y); t5 = D3;
        STEP_F(cv6, eb.z); t6 = D3;
        STEP_F(cv7, eb.w); t7 = D3;
        if (edge63) {
          eout[g * 8 + 0] = t0; eout[g * 8 + 1] = t1; eout[g * 8 + 2] = t2; eout[g * 8 + 3] = t3;
          eout[g * 8 + 4] = t4; eout[g * 8 + 5] = t5; eout[g * 8 + 6] = t6; eout[g * 8 + 7] = t7;
        }
      }
    } else {
      // -------- guarded path (first / last block) --------
      int a2 = base;
      for (int s = s_lo; s < s_lo + CH; ++s) {
        const ushort4 cuv = *(const ushort4*)(clb + a2);
        a2 += ROWB;
        if (a2 >= WINROWS * ROWB) a2 -= WINROWS * ROWB;
        const float ev = elds[s & (CH - 1)];
        const float c0 = bf2f(cuv.x), c1 = bf2f(cuv.y), c2 = bf2f(cuv.z), c3 = bf2f(cuv.w);
        const float Lc = dpp_shr1(ev, D3);
        const float h0 = fmaxf(fminf(D0, Lp), c0);
        const float h1 = fmaxf(fminf(D1, D0), c1);
        const float h2 = fmaxf(fminf(D2, D1), c2);
        const float h3 = fmaxf(fminf(D3, D2), c3);
        float x = __builtin_amdgcn_fmed3f(Lc, c0, h0);
        const float n0 = x;
        x = __builtin_amdgcn_fmed3f(x, c1, h1);
        const float n1 = x;
        x = __builtin_amdgcn_fmed3f(x, c2, h2);
        const float n2 = x;
        x = __builtin_amdgcn_fmed3f(x, c3, h3);
        const float n3 = x;
        const int ii = s - lane;
        const bool act = (u32)ii < (u32)N;
        Lp = (s0 && lane == 0) ? HUGEV : Lc;
        if (act) { D0 = n0; D1 = n1; D2 = n2; D3 = n3; }
        if (do_edge && act && lane == 63) eout[s - s_lo] = n3;
      }
    }

    // (d) edge epilogue: coalesced store + publish
    if (do_edge) {
      asm volatile("s_waitcnt lgkmcnt(0)" ::: "memory");
      __builtin_amdgcn_sched_barrier(0);
      const int r = s_lo - 63 + lane;
      if (r >= 0 && r < N) {
        const float v = eout[lane];
        __hip_atomic_store(edge + (size_t)S * N + r, v, __ATOMIC_RELAXED, __HIP_MEMORY_SCOPE_AGENT);
      }
      asm volatile("s_waitcnt vmcnt(0)" ::: "memory");
      const int done = ((s_lo + CH < TOTSTEP) ? (s_lo + CH) : TOTSTEP) - 63;
      if (lane == 0)
        __hip_atomic_store(prog + S, done, __ATOMIC_RELEASE, __HIP_MEMORY_SCOPE_AGENT);
    }

    // (e) prefetch chunk q+2 (lands during block q+1)
    if (q + 2 < NCHUNK) STAGE(q + 2);
  }

  if (S == NSTRIP - 1 && lane == 63) out[0] = sqrtf(fmaxf(D3, 0.0f));
}

extern "C" void kernel_launch(void* const* d_in, const int* in_sizes, int n_in,
                              void* d_out, int out_size, void* d_ws, size_t ws_size,
                              hipStream_t stream) {
  const float* pred = (const float*)d_in[0];
  const float* tgt  = (const float*)d_in[1];
  char* ws = (char*)d_ws;
  u16* C2   = (u16*)ws;                                   // 32 MB
  float* na = (float*)(ws + (size_t)N * N * 2);
  float* nb = na + N;
  float* edge = nb + N;
  int* prog = (int*)(edge + (size_t)NSTRIP * N);
  float* out = (float*)d_out;

  hipLaunchKernelGGL(norms_kernel, dim3(2048), dim3(256), 0, stream, pred, tgt, na, nb, prog);
  hipLaunchKernelGGL(gemm_kernel, dim3(32, 32), dim3(256), 0, stream, pred, tgt, na, nb, C2);
  hipLaunchKernelGGL(dp_kernel, dim3(NSTRIP), dim3(64), 0, stream, C2, edge, prog, out);
}